// Round 9
// baseline (115.140 us; speedup 1.0000x reference)
//
#include <hip/hip_runtime.h>
#include <cstdint>
#include <cstddef>

#define NB 64
#define NA 4096
#define ND 512

typedef float f32x4 __attribute__((ext_vector_type(4)));

// ws layout (16 KB, proven safe since R4): words t*16 (t<256) = hierarchical
// min slots; word 4081 = mask-dtype flag.
#define WS_FLAG 4081

// ---------- float <-> order-preserving unsigned encoding (for atomicMin) ----------
__device__ __forceinline__ unsigned enc_f(float f){
  unsigned b = __float_as_uint(f);
  return (b & 0x80000000u) ? ~b : (b | 0x80000000u);
}
__device__ __forceinline__ float dec_f(unsigned e){
  unsigned b = (e & 0x80000000u) ? (e ^ 0x80000000u) : ~e;
  return __uint_as_float(b);
}

// ---------- JAX threefry2x32, key = jax.random.key(42) -> (0, 42) ----------
// Partitionable path: per flat element n, pair = (0, n); sub-64-bit widths
// XOR-fold the two output words: bits = x0_final ^ x1_final.  (verified R3)
__device__ __forceinline__ unsigned rotl32(unsigned x, int d){ return (x << d) | (x >> (32 - d)); }

__device__ unsigned threefry_bits(unsigned n){
  const unsigned ks0 = 0u;
  const unsigned ks1 = 42u;
  const unsigned ks2 = 0x1BD11BDAu ^ ks0 ^ ks1;
  unsigned x0 = 0u;
  unsigned x1 = n;
  x0 += ks0; x1 += ks1;
  const int r0[4] = {13, 15, 26, 6};
  const int r1[4] = {17, 29, 16, 24};
  #pragma unroll
  for (int j = 0; j < 4; j++){ x0 += x1; x1 = rotl32(x1, r0[j]); x1 ^= x0; }
  x0 += ks1; x1 += ks2 + 1u;
  #pragma unroll
  for (int j = 0; j < 4; j++){ x0 += x1; x1 = rotl32(x1, r1[j]); x1 ^= x0; }
  x0 += ks2; x1 += ks0 + 2u;
  #pragma unroll
  for (int j = 0; j < 4; j++){ x0 += x1; x1 = rotl32(x1, r0[j]); x1 ^= x0; }
  x0 += ks0; x1 += ks1 + 3u;
  #pragma unroll
  for (int j = 0; j < 4; j++){ x0 += x1; x1 = rotl32(x1, r1[j]); x1 ^= x0; }
  x0 += ks1; x1 += ks2 + 4u;
  #pragma unroll
  for (int j = 0; j < 4; j++){ x0 += x1; x1 = rotl32(x1, r0[j]); x1 ^= x0; }
  x0 += ks2; x1 += ks0 + 5u;
  return x0 ^ x1;
}

// ---------- init: min slots + mask dtype detect (first 4096 u32 = 16 KB) ----------
__global__ __launch_bounds__(256) void init_ws(unsigned* __restrict__ ws,
                                               const unsigned* __restrict__ m32){
  __shared__ int bad;
  int t = threadIdx.x;
  if (t == 0) bad = 0;
  ws[t * 16] = 0xFFFFFFFFu;
  __syncthreads();
  for (int i = t; i < 4096; i += 256)
    if (m32[i] > 1u) bad = 1;              // benign race, only 1 written
  __syncthreads();
  if (t == 0) ws[WS_FLAG] = bad ? 0u : 1u; // 1 => int32 mask, 0 => byte mask
}

// ---------- logits + hierarchical global-min : one wave per action, 16/block ----------
__global__ __launch_bounds__(1024) void dot_kernel(const float* __restrict__ s,
                                                   const float* __restrict__ ae,
                                                   float* __restrict__ logits,
                                                   unsigned* __restrict__ minw){
  __shared__ unsigned sm[16];
  int wave = threadIdx.x >> 6;
  int lane = threadIdx.x & 63;
  int blk  = blockIdx.x;          // 16384 blocks: b = blk>>8, 16 actions per block
  int b = blk >> 8;
  int a = ((blk & 255) << 4) | wave;
  const float* ar = ae + (size_t)(b * NA + a) * ND;
  const float* sr = s + b * ND;
  // a_embeds: zero-reuse stream -> nontemporal (no L2/L3 allocation)  [R8: -15us]
  f32x4 a0 = __builtin_nontemporal_load((const f32x4*)(ar + lane * 4));
  f32x4 a1 = __builtin_nontemporal_load((const f32x4*)(ar + 256 + lane * 4));
  // s_embed: reused by all blocks of the same row -> cached load
  f32x4 s0 = *(const f32x4*)(sr + lane * 4);
  f32x4 s1 = *(const f32x4*)(sr + 256 + lane * 4);
  float p = a0.x*s0.x + a0.y*s0.y + a0.z*s0.z + a0.w*s0.w
          + a1.x*s1.x + a1.y*s1.y + a1.z*s1.z + a1.w*s1.w;
  #pragma unroll
  for (int off = 32; off > 0; off >>= 1) p += __shfl_xor(p, off, 64);
  if (lane == 0){
    logits[(size_t)b * NA + a] = p;
    sm[wave] = enc_f(p);
  }
  __syncthreads();
  if (threadIdx.x == 0){
    unsigned m = sm[0];
    #pragma unroll
    for (int w = 1; w < 16; w++) m = sm[w] < m ? sm[w] : m;
    atomicMin(minw + (blk & 255) * 16, m);   // 64 contenders per slot
  }
}

// ---------- per row: fold min, mask-fill, register top-5, gumbel sample ----------
__global__ __launch_bounds__(1024) void row_kernel(float* __restrict__ out,
                                                   const void* __restrict__ maskp,
                                                   const unsigned* __restrict__ ws,
                                                   const unsigned* __restrict__ alpha_raw){
  __shared__ unsigned su[16];
  __shared__ float rv[16]; __shared__ int ri[16];
  __shared__ float selv[5]; __shared__ int seli[5];
  __shared__ int swin;
  __shared__ float s_fill;
  int b = blockIdx.x;
  int t = threadIdx.x;
  float* lrow = out + NB + (size_t)b * NA;
  const unsigned char* m8  = (const unsigned char*)maskp;
  const unsigned*      m32 = (const unsigned*)maskp;
  int mflag = (int)ws[WS_FLAG];

  // -- fold 256 hierarchical min slots (threads 0..255)
  unsigned e = (t < 256) ? ws[t * 16] : 0xFFFFFFFFu;
  #pragma unroll
  for (int off = 32; off > 0; off >>= 1){
    unsigned o = __shfl_xor(e, off, 64);
    e = o < e ? o : e;
  }
  if ((t & 63) == 0) su[t >> 6] = e;
  __syncthreads();
  if (t == 0){
    unsigned r = su[0];
    #pragma unroll
    for (int w = 1; w < 16; w++) r = su[w] < r ? su[w] : r;
    s_fill = dec_f(r) - 1.0f;
  }
  __syncthreads();
  float fill = s_fill;

  // -- mask-fill row in place; keep 4 values per thread in registers
  float v0, v1, v2, v3;
  {
    int i0 = b * NA + t;
    bool a0 = mflag ? (m32[i0] != 0u) : (m8[i0] != 0);
    bool a1 = mflag ? (m32[i0 + 1024] != 0u) : (m8[i0 + 1024] != 0);
    bool a2 = mflag ? (m32[i0 + 2048] != 0u) : (m8[i0 + 2048] != 0);
    bool a3 = mflag ? (m32[i0 + 3072] != 0u) : (m8[i0 + 3072] != 0);
    v0 = a0 ? lrow[t]        : fill;
    v1 = a1 ? lrow[t + 1024] : fill;
    v2 = a2 ? lrow[t + 2048] : fill;
    v3 = a3 ? lrow[t + 3072] : fill;
    lrow[t]        = v0;
    lrow[t + 1024] = v1;
    lrow[t + 2048] = v2;
    lrow[t + 3072] = v3;
  }

  // -- top-5: 5 passes over register values (smallest-index tie-break)
  for (int k = 0; k < 5; k++){
    float bv = v0; int bi = t;                         // ascending index scan
    if (v1 > bv){ bv = v1; bi = t + 1024; }
    if (v2 > bv){ bv = v2; bi = t + 2048; }
    if (v3 > bv){ bv = v3; bi = t + 3072; }
    #pragma unroll
    for (int off = 32; off > 0; off >>= 1){
      float ov = __shfl_xor(bv, off, 64);
      int   oi = __shfl_xor(bi, off, 64);
      if (ov > bv || (ov == bv && oi < bi)){ bv = ov; bi = oi; }
    }
    if ((t & 63) == 0){ rv[t >> 6] = bv; ri[t >> 6] = bi; }
    __syncthreads();
    if (t == 0){
      float fv = rv[0]; int fi = ri[0];
      #pragma unroll
      for (int w = 1; w < 16; w++)
        if (rv[w] > fv || (rv[w] == fv && ri[w] < fi)){ fv = rv[w]; fi = ri[w]; }
      selv[k] = fv; seli[k] = fi; swin = fi;
    }
    __syncthreads();
    int wi = swin;                                     // clear winner's register
    if (wi == t)            v0 = -INFINITY;
    else if (wi == t + 1024) v1 = -INFINITY;
    else if (wi == t + 2048) v2 = -INFINITY;
    else if (wi == t + 3072) v3 = -INFINITY;
  }

  // -- gumbel-argmax sample over keep = available & top5
  if (t == 0){
    unsigned ab = *alpha_raw;   // int scalar or float bits — disambiguate
    float alpha = (ab < 0x00800000u) ? (float)(int)ab : __uint_as_float(ab);
    float best = -INFINITY; int ba = 0;
    for (int k = 0; k < 5; k++){
      int idx  = seli[k];
      int gidx = b * NA + idx;
      bool av = mflag ? (m32[gidx] != 0u) : (m8[gidx] != 0);
      if (!av) continue;
      unsigned bits = threefry_bits((unsigned)gidx);
      float f = __uint_as_float((bits >> 9) | 0x3F800000u) - 1.0f;  // [0,1)
      const float tiny = 1.17549435e-38f;
      float u = fmaxf(tiny, f + tiny);
      float g = -logf(-logf(u));
      // argmax(log softmax_renorm) + g  ==  argmax(l/alpha + g) over keep set
      float sc = selv[k] / alpha + g;
      if (sc > best){ best = sc; ba = idx; }
    }
    out[b] = (float)ba;
  }
}

extern "C" void kernel_launch(void* const* d_in, const int* in_sizes, int n_in,
                              void* d_out, int out_size, void* d_ws, size_t ws_size,
                              hipStream_t stream){
  const float*    s     = (const float*)d_in[0];
  const float*    ae    = (const float*)d_in[1];
  const void*     mask  = d_in[2];
  const unsigned* alpha = (const unsigned*)d_in[3];
  float*    out = (float*)d_out;
  unsigned* ws  = (unsigned*)d_ws;

  hipLaunchKernelGGL(init_ws,    dim3(1),            dim3(256),  0, stream,
                     ws, (const unsigned*)mask);
  hipLaunchKernelGGL(dot_kernel, dim3(NB * NA / 16), dim3(1024), 0, stream,
                     s, ae, out + NB, ws);
  hipLaunchKernelGGL(row_kernel, dim3(NB),           dim3(1024), 0, stream,
                     out, mask, ws, alpha);
}